// Round 2
// baseline (11318.005 us; speedup 1.0000x reference)
//
#include <hip/hip_runtime.h>
#include <hip/hip_bf16.h>
#include <cmath>

// Problem dims
#define Bb 128
#define Tt 512
#define Ii 512
#define Hh 2048
#define Oo 512
#define REC_GRID 256

typedef __bf16 bf16_t;
typedef __bf16 bf16x8 __attribute__((ext_vector_type(8)));
typedef __bf16 bf16x4 __attribute__((ext_vector_type(4)));
typedef float  f32x4_t __attribute__((ext_vector_type(4)));

static __device__ __forceinline__ bf16_t to_b(float v){ return (bf16_t)v; }

// ---------- small prep kernels ----------
__global__ __launch_bounds__(256) void k_f2b(bf16_t* __restrict__ dst, const float* __restrict__ src){
  size_t i = ((size_t)blockIdx.x*256 + threadIdx.x)*4;
  float4 v = *(const float4*)(src + i);
  bf16x4 o; o[0]=to_b(v.x); o[1]=to_b(v.y); o[2]=to_b(v.z); o[3]=to_b(v.w);
  *(bf16x4*)(dst + i) = o;
}

// h0[b][i] = hi_w[i] + hi_b[i]  (broadcast over batch) -> bf16 A-source for step 0
__global__ __launch_bounds__(256) void k_init_h0(const float* __restrict__ hi_w, const float* __restrict__ hi_b,
                                                 bf16_t* __restrict__ h0b){
  int i = blockIdx.x*256 + threadIdx.x;           // [0, H)
  bf16_t vb = to_b(hi_w[i] + hi_b[i]);
  for (int b=0;b<Bb;++b) h0b[(size_t)b*Hh + i] = vb;
}

// x[B,T,I] f32 -> x_tm[T,B,I] bf16  (time-major rows for the encoder GEMM)
__global__ __launch_bounds__(256) void k_convert_x(const float* __restrict__ x, bf16_t* __restrict__ x_tm){
  size_t idx = ((size_t)blockIdx.x*256 + threadIdx.x)*8;
  int    i0  = (int)(idx % Ii);
  size_t m   = idx / Ii;                          // m = t*B + b
  int    t   = (int)(m / Bb), b = (int)(m % Bb);
  const float* s = x + ((size_t)b*Tt + t)*Ii + i0;
  float4 v0 = *(const float4*)s, v1 = *(const float4*)(s+4);
  bf16x8 o;
  o[0]=to_b(v0.x); o[1]=to_b(v0.y); o[2]=to_b(v0.z); o[3]=to_b(v0.w);
  o[4]=to_b(v1.x); o[5]=to_b(v1.y); o[6]=to_b(v1.z); o[7]=to_b(v1.w);
  *(bf16x8*)(x_tm + idx) = o;
}

// ---------- GEMM building blocks (encoder / decoder) ----------
template<int ROWS, int KB>
static __device__ __forceinline__ void stage(const bf16_t* __restrict__ g, long ld, long row0, int k0,
                                             char* __restrict__ ldsT){
  constexpr int SLOTS = KB/8;            // 16B chunks per row
  constexpr int PT    = ROWS*SLOTS/256;  // chunks per thread
  #pragma unroll
  for (int j=0;j<PT;++j){
    int c    = threadIdx.x + 256*j;
    int row  = c / SLOTS, slot = c % SLOTS;
    uint4 v  = *(const uint4*)(g + (row0+row)*ld + k0 + slot*8);
    *(uint4*)(ldsT + row*(KB*2) + ((slot*16) ^ ((row&7)<<4))) = v;
  }
}

template<int KB>
static __device__ __forceinline__ bf16x8 frag(const char* __restrict__ ldsT, int row, int kk, int lane){
  int kbyte = kk*64 + ((lane>>4)<<4);    // k elem = kk*32 + (lane>>4)*8, *2 bytes
  return *(const bf16x8*)(ldsT + row*(KB*2) + (kbyte ^ ((row&7)<<4)));
}

// Generic 128x128-tile GEMM: C[m,n] = sum_k A[m,k]*B[n,k] + bias[n]
// EPI=0: bf16 output (encoder -> EH). EPI=1: f32 output (decoder -> d_out).
template<int EPI>
__global__ __launch_bounds__(256) void gemm128(const bf16_t* __restrict__ A, long lda,
                                               const bf16_t* __restrict__ Bw, long ldb,
                                               const float* __restrict__ bias,
                                               void* __restrict__ Cout, long ldc, int K){
  constexpr int TM=128, TN=128, KB=64;
  __shared__ char lds[(TM+TN)*KB*2];     // 32 KiB
  char* ldsA = lds;
  char* ldsB = lds + TM*KB*2;
  long m0 = (long)blockIdx.x * TM;
  long n0 = (long)blockIdx.y * TN;
  int w = threadIdx.x >> 6, lane = threadIdx.x & 63;
  int wm = w >> 1, wn = w & 1;           // 2x2 waves, 64x64 per wave
  f32x4_t acc[4][4] = {};
  for (int k0=0;k0<K;k0+=KB){
    __syncthreads();
    stage<TM,KB>(A,  lda, m0, k0, ldsA);
    stage<TN,KB>(Bw, ldb, n0, k0, ldsB);
    __syncthreads();
    #pragma unroll
    for (int kk=0;kk<KB/32;++kk){
      bf16x8 af[4], bfv[4];
      #pragma unroll
      for (int f=0;f<4;++f){ int r = wm*64 + f*16 + (lane&15); af[f]  = frag<KB>(ldsA, r, kk, lane); }
      #pragma unroll
      for (int f=0;f<4;++f){ int r = wn*64 + f*16 + (lane&15); bfv[f] = frag<KB>(ldsB, r, kk, lane); }
      #pragma unroll
      for (int i=0;i<4;++i)
        #pragma unroll
        for (int j=0;j<4;++j)
          acc[i][j] = __builtin_amdgcn_mfma_f32_16x16x32_bf16(af[i], bfv[j], acc[i][j], 0,0,0);
    }
  }
  #pragma unroll
  for (int i=0;i<4;++i)
    #pragma unroll
    for (int j=0;j<4;++j)
      #pragma unroll
      for (int e=0;e<4;++e){
        long row = m0 + wm*64 + i*16 + ((lane>>4)<<2) + e;   // C row = (lane>>4)*4+reg  [m89]
        long col = n0 + wn*64 + j*16 + (lane&15);            // C col = lane&15
        float v = acc[i][j][e] + bias[col];
        if (EPI==0) ((bf16_t*)Cout)[row*ldc + col] = to_b(v);
        else        ((float*) Cout)[row*ldc + col] = v;
      }
}

// ---------- custom device-scope grid barrier ----------
// slots: one 128B-strided word per block (written with release by that block),
// rel: single release flag written by block 0 after gathering all slots.
static __device__ __forceinline__ void gbar(unsigned* __restrict__ slots, unsigned* __restrict__ rel,
                                            int bid, unsigned gen){
  __syncthreads();   // all of this block's h-stores are in L2 (barrier drains vmcnt)
  if (bid != 0){
    if (threadIdx.x == 0){
      __threadfence();                                   // agent release (L2 writeback)
      __hip_atomic_store(slots + bid*32, gen, __ATOMIC_RELEASE, __HIP_MEMORY_SCOPE_AGENT);
      unsigned v;
      do { v = __hip_atomic_load(rel, __ATOMIC_RELAXED, __HIP_MEMORY_SCOPE_AGENT); } while (v < gen);
      __threadfence();                                   // agent acquire (invalidate stale L1/L2)
    }
    __syncthreads();
  } else {
    int tid = threadIdx.x;
    if (tid >= 1){                                       // thread t polls block t's slot
      unsigned v;
      do { v = __hip_atomic_load(slots + tid*32, __ATOMIC_RELAXED, __HIP_MEMORY_SCOPE_AGENT); } while (v < gen);
    }
    __syncthreads();                                     // all 255 slots observed
    if (tid == 0){
      __threadfence();                                   // acquire others' writes / release own
      __hip_atomic_store(rel, gen, __ATOMIC_RELEASE, __HIP_MEMORY_SCOPE_AGENT);
    }
    __syncthreads();
  }
}

// ---------- persistent recurrence kernel ----------
// Block bid owns output tile: batch rows m0..m0+31, H cols n0..n0+31.
// W[n0:n0+32, 0:2048] staged once into LDS (128 KB, swizzled); per step:
// A-frags read straight from global (h_prev bf16), B-frags from LDS, 1 MFMA/kk.
// f32 master h for this lane's 4 C-elements lives in registers for all 512 steps.
__global__ __launch_bounds__(256, 1) void rec_persist(
    const bf16_t* __restrict__ h0b, const bf16_t* __restrict__ W,
    bf16_t* __restrict__ EH, float* __restrict__ hfinal,
    const float* __restrict__ rec_b, const float* __restrict__ hi_w, const float* __restrict__ hi_b,
    const float* __restrict__ dtp, const float* __restrict__ ap,
    unsigned* __restrict__ slots, unsigned* __restrict__ rel)
{
  __shared__ uint4 lds4[131072/16];      // 128 KB: W slice, 32 rows x 4096 B, swizzled
  char* lds = (char*)lds4;
  const int bid = blockIdx.x;
  const int m0 = (bid & 3) * 32;         // batch tile (4)
  const int n0 = (bid >> 2) * 32;        // H tile (64)
  const int w = threadIdx.x >> 6, lane = threadIdx.x & 63;
  const int wm = w >> 1, wn = w & 1;     // 2x2 waves, 16x16 per wave

  // stage W rows n0..n0+31 (coalesced: 256 threads x 16B = one 4KB row per iter)
  for (int r = 0; r < 32; ++r){
    uint4 v = *(const uint4*)(W + (size_t)(n0 + r)*Hh + threadIdx.x*8);
    *(uint4*)(lds + r*4096 + ((threadIdx.x*16) ^ ((r&7)<<4))) = v;
  }
  __syncthreads();

  const float s  = 1.f/(1.f + __expf(-dtp[0]));
  const float av = ap[0];
  const int   mycol = n0 + wn*16 + (lane&15);          // global H col of acc
  const float rb = rec_b[mycol];
  const int   alane = (lane>>4)<<3;                    // A k sub-offset (elems)
  const char* bbase = lds + (wn*16 + (lane&15))*4096;  // B frag row base
  const int   bxor  = ((wn*16 + (lane&15)) & 7) << 4;
  const int   kb2   = alane*2;                         // A k sub-offset in bytes

  // f32 master h (same init value for all 4 rows: h0 is batch-independent)
  float hm[4];
  const float h0v = hi_w[mycol] + hi_b[mycol];
  #pragma unroll
  for (int e=0;e<4;++e) hm[e] = h0v;

  unsigned gen = 0;
  for (int t=0; t<Tt; ++t){
    const bf16_t* Asrc = (t==0) ? h0b : (EH + (size_t)(t-1)*(Bb*Hh));
    const bf16_t* arow = Asrc + (size_t)(m0 + wm*16 + (lane&15))*Hh + alane;
    f32x4_t acc = {0.f,0.f,0.f,0.f};
    #pragma unroll
    for (int kk=0;kk<64;++kk){
      bf16x8 a = *(const bf16x8*)(arow + kk*32);
      bf16x8 b = *(const bf16x8*)(bbase + ((kk*64 + kb2) ^ bxor));
      acc = __builtin_amdgcn_mfma_f32_16x16x32_bf16(a, b, acc, 0,0,0);
    }
    // fused epilogue: h_new = (1-s)*h + s*tanh(enc + av*(r + rec_b))
    bf16_t* EHt = EH + (size_t)t*(Bb*Hh);
    #pragma unroll
    for (int e=0;e<4;++e){
      size_t idx = (size_t)(m0 + wm*16 + ((lane>>4)<<2) + e)*Hh + mycol;
      float enc = (float)EHt[idx];
      float pre = enc + av*(acc[e] + rb);
      float th  = 1.f - 2.f/(__expf(2.f*pre) + 1.f);   // tanh
      hm[e] = (1.f - s)*hm[e] + s*th;
      EHt[idx] = to_b(hm[e]);
    }
    gbar(slots, rel, bid, ++gen);
  }
  // final hidden (f32) -> out tail
  #pragma unroll
  for (int e=0;e<4;++e){
    size_t idx = (size_t)(m0 + wm*16 + ((lane>>4)<<2) + e)*Hh + mycol;
    hfinal[idx] = hm[e];
  }
}

// ---------- launch ----------
extern "C" void kernel_launch(void* const* d_in, const int* in_sizes, int n_in,
                              void* d_out, int out_size, void* d_ws, size_t ws_size,
                              hipStream_t stream){
  const float* x     = (const float*)d_in[0];
  const float* dt    = (const float*)d_in[1];
  const float* a     = (const float*)d_in[2];
  const float* enc_w = (const float*)d_in[3];
  const float* enc_b = (const float*)d_in[4];
  const float* rec_w = (const float*)d_in[5];
  const float* rec_b = (const float*)d_in[6];
  const float* dec_w = (const float*)d_in[7];
  const float* dec_b = (const float*)d_in[8];
  const float* hi_w  = (const float*)d_in[9];
  const float* hi_b  = (const float*)d_in[10];
  float* out = (float*)d_out;

  // workspace carve-out (~333 MB)
  char* ws = (char*)d_ws;
  size_t off = 0;
  auto carve = [&](size_t bytes)->char*{ char* p = ws + off; off += (bytes + 255) & ~(size_t)255; return p; };
  bf16_t* x_tm   = (bf16_t*)carve((size_t)Tt*Bb*Ii*2);   // 64 MB
  bf16_t* EH     = (bf16_t*)carve((size_t)Tt*Bb*Hh*2);   // 256 MB  enc -> h history
  bf16_t* h0b    = (bf16_t*)carve((size_t)Bb*Hh*2);
  bf16_t* enc_wb = (bf16_t*)carve((size_t)Hh*Ii*2);
  bf16_t* rec_wb = (bf16_t*)carve((size_t)Hh*Hh*2);
  bf16_t* dec_wb = (bf16_t*)carve((size_t)Oo*Hh*2);
  unsigned* bar  = (unsigned*)carve(REC_GRID*32*4 + 128); // slots + rel
  if (off > ws_size) return;  // diagnostic: leaves output zeroed

  unsigned* slots = bar;
  unsigned* rel   = bar + REC_GRID*32;

  // reset barrier state every call (harness does not re-poison ws between replays)
  hipMemsetAsync(bar, 0, REC_GRID*32*4 + 128, stream);

  // weights -> bf16
  k_f2b<<<(Hh*Ii)/1024, 256, 0, stream>>>(enc_wb, enc_w);
  k_f2b<<<(Hh*Hh)/1024, 256, 0, stream>>>(rec_wb, rec_w);
  k_f2b<<<(Oo*Hh)/1024, 256, 0, stream>>>(dec_wb, dec_w);
  k_init_h0<<<Hh/256, 256, 0, stream>>>(hi_w, hi_b, h0b);
  k_convert_x<<<((size_t)Tt*Bb*Ii/8)/256, 256, 0, stream>>>(x, x_tm);

  // encoder: EH[t*B+b, h] = x_tm @ enc_w^T + enc_b   (M=65536, K=512, N=2048)
  gemm128<0><<<dim3((Tt*Bb)/128, Hh/128), 256, 0, stream>>>(x_tm, Ii, enc_wb, Ii, enc_b, EH, Hh, Ii);

  // recurrence: one persistent cooperative kernel, 512 steps with device barrier
  {
    float* hfinal = out + (size_t)Tt*Bb*Oo;
    void* args[] = { (void*)&h0b, (void*)&rec_wb, (void*)&EH, (void*)&hfinal,
                     (void*)&rec_b, (void*)&hi_w, (void*)&hi_b, (void*)&dt, (void*)&a,
                     (void*)&slots, (void*)&rel };
    hipLaunchCooperativeKernel((const void*)rec_persist, dim3(REC_GRID), dim3(256), args, 0, stream);
  }

  // decoder: out[t*B+b, o] = EH @ dec_w^T + dec_b   (M=65536, K=2048, N=512)
  gemm128<1><<<dim3((Tt*Bb)/128, Oo/128), 256, 0, stream>>>(EH, Hh, dec_wb, Hh, dec_b, out, Oo, Hh);
}

// Round 3
// 5197.520 us; speedup vs baseline: 2.1776x; 2.1776x over previous
//
#include <hip/hip_runtime.h>
#include <hip/hip_bf16.h>
#include <cmath>

// Problem dims
#define Bb 128
#define Tt 512
#define Ii 512
#define Hh 2048
#define Oo 512
#define REC_GRID 256

typedef __bf16 bf16_t;
typedef __bf16 bf16x8 __attribute__((ext_vector_type(8)));
typedef __bf16 bf16x4 __attribute__((ext_vector_type(4)));
typedef float  f32x4_t __attribute__((ext_vector_type(4)));
typedef unsigned long long u64;

static __device__ __forceinline__ bf16_t to_b(float v){ return (bf16_t)v; }
static __device__ __forceinline__ float  b2f(unsigned short u){ unsigned x = ((unsigned)u)<<16; return __builtin_bit_cast(float, x); }
static __device__ __forceinline__ unsigned short f2bbits(float v){ return __builtin_bit_cast(unsigned short, to_b(v)); }

// ---------- small prep kernels ----------
__global__ __launch_bounds__(256) void k_f2b(bf16_t* __restrict__ dst, const float* __restrict__ src){
  size_t i = ((size_t)blockIdx.x*256 + threadIdx.x)*4;
  float4 v = *(const float4*)(src + i);
  bf16x4 o; o[0]=to_b(v.x); o[1]=to_b(v.y); o[2]=to_b(v.z); o[3]=to_b(v.w);
  *(bf16x4*)(dst + i) = o;
}

// h0[b][i] = hi_w[i] + hi_b[i]  (broadcast over batch) -> bf16 A-source for step 0
__global__ __launch_bounds__(256) void k_init_h0(const float* __restrict__ hi_w, const float* __restrict__ hi_b,
                                                 bf16_t* __restrict__ h0b){
  int i = blockIdx.x*256 + threadIdx.x;           // [0, H)
  bf16_t vb = to_b(hi_w[i] + hi_b[i]);
  for (int b=0;b<Bb;++b) h0b[(size_t)b*Hh + i] = vb;
}

// x[B,T,I] f32 -> x_tm[T,B,I] bf16  (time-major rows for the encoder GEMM)
__global__ __launch_bounds__(256) void k_convert_x(const float* __restrict__ x, bf16_t* __restrict__ x_tm){
  size_t idx = ((size_t)blockIdx.x*256 + threadIdx.x)*8;
  int    i0  = (int)(idx % Ii);
  size_t m   = idx / Ii;                          // m = t*B + b
  int    t   = (int)(m / Bb), b = (int)(m % Bb);
  const float* s = x + ((size_t)b*Tt + t)*Ii + i0;
  float4 v0 = *(const float4*)s, v1 = *(const float4*)(s+4);
  bf16x8 o;
  o[0]=to_b(v0.x); o[1]=to_b(v0.y); o[2]=to_b(v0.z); o[3]=to_b(v0.w);
  o[4]=to_b(v1.x); o[5]=to_b(v1.y); o[6]=to_b(v1.z); o[7]=to_b(v1.w);
  *(bf16x8*)(x_tm + idx) = o;
}

// ---------- GEMM building blocks (encoder / decoder) ----------
template<int ROWS, int KB>
static __device__ __forceinline__ void stage(const bf16_t* __restrict__ g, long ld, long row0, int k0,
                                             char* __restrict__ ldsT){
  constexpr int SLOTS = KB/8;            // 16B chunks per row
  constexpr int PT    = ROWS*SLOTS/256;  // chunks per thread
  #pragma unroll
  for (int j=0;j<PT;++j){
    int c    = threadIdx.x + 256*j;
    int row  = c / SLOTS, slot = c % SLOTS;
    uint4 v  = *(const uint4*)(g + (row0+row)*ld + k0 + slot*8);
    *(uint4*)(ldsT + row*(KB*2) + ((slot*16) ^ ((row&7)<<4))) = v;
  }
}

template<int KB>
static __device__ __forceinline__ bf16x8 frag(const char* __restrict__ ldsT, int row, int kk, int lane){
  int kbyte = kk*64 + ((lane>>4)<<4);    // k elem = kk*32 + (lane>>4)*8, *2 bytes
  return *(const bf16x8*)(ldsT + row*(KB*2) + (kbyte ^ ((row&7)<<4)));
}

// Generic 128x128-tile GEMM: C[m,n] = sum_k A[m,k]*B[n,k] + bias[n]
// EPI=0: bf16 output (encoder -> EH). EPI=1: f32 output (decoder -> d_out).
template<int EPI>
__global__ __launch_bounds__(256) void gemm128(const bf16_t* __restrict__ A, long lda,
                                               const bf16_t* __restrict__ Bw, long ldb,
                                               const float* __restrict__ bias,
                                               void* __restrict__ Cout, long ldc, int K){
  constexpr int TM=128, TN=128, KB=64;
  __shared__ char lds[(TM+TN)*KB*2];     // 32 KiB
  char* ldsA = lds;
  char* ldsB = lds + TM*KB*2;
  long m0 = (long)blockIdx.x * TM;
  long n0 = (long)blockIdx.y * TN;
  int w = threadIdx.x >> 6, lane = threadIdx.x & 63;
  int wm = w >> 1, wn = w & 1;           // 2x2 waves, 64x64 per wave
  f32x4_t acc[4][4] = {};
  for (int k0=0;k0<K;k0+=KB){
    __syncthreads();
    stage<TM,KB>(A,  lda, m0, k0, ldsA);
    stage<TN,KB>(Bw, ldb, n0, k0, ldsB);
    __syncthreads();
    #pragma unroll
    for (int kk=0;kk<KB/32;++kk){
      bf16x8 af[4], bfv[4];
      #pragma unroll
      for (int f=0;f<4;++f){ int r = wm*64 + f*16 + (lane&15); af[f]  = frag<KB>(ldsA, r, kk, lane); }
      #pragma unroll
      for (int f=0;f<4;++f){ int r = wn*64 + f*16 + (lane&15); bfv[f] = frag<KB>(ldsB, r, kk, lane); }
      #pragma unroll
      for (int i=0;i<4;++i)
        #pragma unroll
        for (int j=0;j<4;++j)
          acc[i][j] = __builtin_amdgcn_mfma_f32_16x16x32_bf16(af[i], bfv[j], acc[i][j], 0,0,0);
    }
  }
  #pragma unroll
  for (int i=0;i<4;++i)
    #pragma unroll
    for (int j=0;j<4;++j)
      #pragma unroll
      for (int e=0;e<4;++e){
        long row = m0 + wm*64 + i*16 + ((lane>>4)<<2) + e;   // C row = (lane>>4)*4+reg  [m89]
        long col = n0 + wn*64 + j*16 + (lane&15);            // C col = lane&15
        float v = acc[i][j][e] + bias[col];
        if (EPI==0) ((bf16_t*)Cout)[row*ldc + col] = to_b(v);
        else        ((float*) Cout)[row*ldc + col] = v;
      }
}

// ---------- persistent recurrence kernel ----------
// 4 independent groups of 64 blocks. Group g owns batches 32g..32g+31.
// Block (g,n) owns H-cols 32n..32n+31 for those batches; W slice (128 KB)
// lives in LDS for the whole kernel. Swapped MFMA operands (a=W, b=h) make
// each lane's C-fragment 4 CONSECUTIVE H-cols at one batch -> the per-step
// enc-read / h-write is a single aligned u64 agent-scope atomic (write-through
// to MALL, no L2 dirty lines, no fences). Barrier = per-group flat 64-slot
// poll; no __threadfence, no L2 writeback.
__global__ __launch_bounds__(256, 1) void rec_persist(
    const bf16_t* __restrict__ h0b, const bf16_t* __restrict__ W,
    bf16_t* __restrict__ EH, float* __restrict__ hfinal,
    const float* __restrict__ rec_b, const float* __restrict__ hi_w, const float* __restrict__ hi_b,
    const float* __restrict__ dtp, const float* __restrict__ ap,
    unsigned* __restrict__ flags)
{
  __shared__ uint4 lds4[131072/16];      // 128 KB: W slice, 32 rows x 4096 B, swizzled
  char* lds = (char*)lds4;
  const int bid = blockIdx.x;
  const int g   = (bid >> 1) & 3;                 // batch group (XCD-pair if round-robin)
  const int n   = ((bid >> 3) << 1) | (bid & 1);  // H tile 0..63
  const int m0  = g * 32;                         // batch base
  const int n0  = n * 32;                         // H col base
  unsigned* gslots = flags + g*64*32;             // this group's 64 slots (128B stride)
  const int tid = threadIdx.x, w = tid >> 6, lane = tid & 63;
  const int boff = (w & 1) * 16, hoff = (w >> 1) * 16;

  // stage W rows n0..n0+31 (coalesced: 256 threads x 16B = one 4KB row per iter)
  for (int r = 0; r < 32; ++r){
    uint4 v = *(const uint4*)(W + (size_t)(n0 + r)*Hh + tid*8);
    *(uint4*)(lds + r*4096 + ((tid*16) ^ ((r&7)<<4))) = v;
  }
  __syncthreads();

  const float s  = 1.f/(1.f + __expf(-dtp[0]));
  const float av = ap[0];
  const int   batch = m0 + boff + (lane & 15);          // C col = lane&15 -> batch
  const int   hcol0 = n0 + hoff + ((lane >> 4) << 2);   // C row = (lane>>4)*4+e -> H col
  float rb[4], hm[4];
  #pragma unroll
  for (int e=0;e<4;++e){ rb[e] = rec_b[hcol0+e]; hm[e] = hi_w[hcol0+e] + hi_b[hcol0+e]; }

  // W fragment addressing (A operand): local row = hoff + (lane&15)
  const int   wrow  = hoff + (lane & 15);
  const char* wbase = lds + wrow*4096;
  const int   wxor  = (wrow & 7) << 4;
  const int   ksub  = (lane >> 4) * 16;                 // k sub-offset in bytes

  for (int t = 0; t < Tt; ++t){
    // enc for this lane's 4 output elems: uncached agent load (owner L2 must not cache it)
    u64* ep = (u64*)(EH + (size_t)t*(Bb*Hh) + (size_t)batch*Hh + hcol0);
    u64 ev = __hip_atomic_load(ep, __ATOMIC_RELAXED, __HIP_MEMORY_SCOPE_AGENT);

    const bf16_t* Asrc = (t==0) ? h0b : (EH + (size_t)(t-1)*(Bb*Hh));
    const bf16_t* arow = Asrc + (size_t)batch*Hh + ((lane>>4)<<3);
    f32x4_t acc0 = {0.f,0.f,0.f,0.f}, acc1 = {0.f,0.f,0.f,0.f};
    #pragma unroll
    for (int kk=0;kk<32;++kk){
      bf16x8 b0 = *(const bf16x8*)(arow + kk*32);
      bf16x8 a0 = *(const bf16x8*)(wbase + ((kk*64 + ksub) ^ wxor));
      acc0 = __builtin_amdgcn_mfma_f32_16x16x32_bf16(a0, b0, acc0, 0,0,0);
      bf16x8 b1 = *(const bf16x8*)(arow + (kk+32)*32);
      bf16x8 a1 = *(const bf16x8*)(wbase + (((kk+32)*64 + ksub) ^ wxor));
      acc1 = __builtin_amdgcn_mfma_f32_16x16x32_bf16(a1, b1, acc1, 0,0,0);
    }
    // fused epilogue: h_new = (1-s)*h + s*tanh(enc + av*(r + rec_b)); one u64 write-through
    u64 ov = 0;
    #pragma unroll
    for (int e=0;e<4;++e){
      float enc = b2f((unsigned short)(ev >> (16*e)));
      float pre = enc + av*(acc0[e] + acc1[e] + rb[e]);
      float th  = 1.f - 2.f/(__expf(2.f*pre) + 1.f);    // tanh
      hm[e] = (1.f - s)*hm[e] + s*th;
      ov |= ((u64)f2bbits(hm[e])) << (16*e);
    }
    __hip_atomic_store(ep, ov, __ATOMIC_RELAXED, __HIP_MEMORY_SCOPE_AGENT);

    // ---- group barrier: no fences, no L2 writeback ----
    asm volatile("s_waitcnt vmcnt(0)" ::: "memory");    // our agent stores are globally visible once acked
    __syncthreads();
    unsigned gen = (unsigned)(t + 1);
    if (tid == 0) __hip_atomic_store(gslots + n*32, gen, __ATOMIC_RELAXED, __HIP_MEMORY_SCOPE_AGENT);
    if (tid < 64){
      while (__hip_atomic_load(gslots + tid*32, __ATOMIC_RELAXED, __HIP_MEMORY_SCOPE_AGENT) < gen) {}
    }
    __syncthreads();
  }
  // final hidden (f32) -> out tail
  #pragma unroll
  for (int e=0;e<4;++e) hfinal[(size_t)batch*Hh + hcol0 + e] = hm[e];
}

// ---------- launch ----------
extern "C" void kernel_launch(void* const* d_in, const int* in_sizes, int n_in,
                              void* d_out, int out_size, void* d_ws, size_t ws_size,
                              hipStream_t stream){
  const float* x     = (const float*)d_in[0];
  const float* dt    = (const float*)d_in[1];
  const float* a     = (const float*)d_in[2];
  const float* enc_w = (const float*)d_in[3];
  const float* enc_b = (const float*)d_in[4];
  const float* rec_w = (const float*)d_in[5];
  const float* rec_b = (const float*)d_in[6];
  const float* dec_w = (const float*)d_in[7];
  const float* dec_b = (const float*)d_in[8];
  const float* hi_w  = (const float*)d_in[9];
  const float* hi_b  = (const float*)d_in[10];
  float* out = (float*)d_out;

  // workspace carve-out (~333 MB)
  char* ws = (char*)d_ws;
  size_t off = 0;
  auto carve = [&](size_t bytes)->char*{ char* p = ws + off; off += (bytes + 255) & ~(size_t)255; return p; };
  bf16_t* x_tm   = (bf16_t*)carve((size_t)Tt*Bb*Ii*2);   // 64 MB
  bf16_t* EH     = (bf16_t*)carve((size_t)Tt*Bb*Hh*2);   // 256 MB  enc -> h history
  bf16_t* h0b    = (bf16_t*)carve((size_t)Bb*Hh*2);
  bf16_t* enc_wb = (bf16_t*)carve((size_t)Hh*Ii*2);
  bf16_t* rec_wb = (bf16_t*)carve((size_t)Hh*Hh*2);
  bf16_t* dec_wb = (bf16_t*)carve((size_t)Oo*Hh*2);
  unsigned* flags = (unsigned*)carve(4*64*32*4);          // 4 groups x 64 slots x 128B
  if (off > ws_size) return;  // diagnostic: leaves output zeroed

  // reset barrier state every call (harness does not re-poison ws between replays)
  hipMemsetAsync(flags, 0, 4*64*32*4, stream);

  // weights -> bf16
  k_f2b<<<(Hh*Ii)/1024, 256, 0, stream>>>(enc_wb, enc_w);
  k_f2b<<<(Hh*Hh)/1024, 256, 0, stream>>>(rec_wb, rec_w);
  k_f2b<<<(Oo*Hh)/1024, 256, 0, stream>>>(dec_wb, dec_w);
  k_init_h0<<<Hh/256, 256, 0, stream>>>(hi_w, hi_b, h0b);
  k_convert_x<<<((size_t)Tt*Bb*Ii/8)/256, 256, 0, stream>>>(x, x_tm);

  // encoder: EH[t*B+b, h] = x_tm @ enc_w^T + enc_b   (M=65536, K=512, N=2048)
  gemm128<0><<<dim3((Tt*Bb)/128, Hh/128), 256, 0, stream>>>(x_tm, Ii, enc_wb, Ii, enc_b, EH, Hh, Ii);

  // recurrence: one persistent cooperative kernel, 512 steps, per-group barriers
  {
    float* hfinal = out + (size_t)Tt*Bb*Oo;
    void* args[] = { (void*)&h0b, (void*)&rec_wb, (void*)&EH, (void*)&hfinal,
                     (void*)&rec_b, (void*)&hi_w, (void*)&hi_b, (void*)&dt, (void*)&a,
                     (void*)&flags };
    hipLaunchCooperativeKernel((const void*)rec_persist, dim3(REC_GRID), dim3(256), args, 0, stream);
  }

  // decoder: out[t*B+b, o] = EH @ dec_w^T + dec_b   (M=65536, K=2048, N=512)
  gemm128<1><<<dim3((Tt*Bb)/128, Oo/128), 256, 0, stream>>>(EH, Hh, dec_wb, Hh, dec_b, out, Oo, Hh);
}

// Round 4
// 3652.731 us; speedup vs baseline: 3.0985x; 1.4229x over previous
//
#include <hip/hip_runtime.h>
#include <hip/hip_bf16.h>
#include <cmath>

// Problem dims
#define Bb 128
#define Tt 512
#define Ii 512
#define Hh 2048
#define Oo 512
#define REC_GRID 256
#define NCH 8          // K-chunks per step
#define CHC 256        // cols per chunk
#define CHB (CHC*2)    // bytes per row per chunk

typedef __bf16 bf16_t;
typedef __bf16 bf16x8 __attribute__((ext_vector_type(8)));
typedef __bf16 bf16x4 __attribute__((ext_vector_type(4)));
typedef float  f32x4_t __attribute__((ext_vector_type(4)));
typedef unsigned long long u64;

static __device__ __forceinline__ bf16_t to_b(float v){ return (bf16_t)v; }
static __device__ __forceinline__ float  b2f(unsigned short u){ unsigned x = ((unsigned)u)<<16; return __builtin_bit_cast(float, x); }
static __device__ __forceinline__ unsigned short f2bbits(float v){ return __builtin_bit_cast(unsigned short, to_b(v)); }

// async global->LDS, 16B per lane, linear LDS dest (wave-uniform base + lane*16)
static __device__ __forceinline__ void gl_lds16(const void* g, void* l){
  __builtin_amdgcn_global_load_lds((const __attribute__((address_space(1))) void*)g,
                                   (__attribute__((address_space(3))) void*)l, 16, 0, 0);
}

// ---------- small prep kernels ----------
__global__ __launch_bounds__(256) void k_f2b(bf16_t* __restrict__ dst, const float* __restrict__ src){
  size_t i = ((size_t)blockIdx.x*256 + threadIdx.x)*4;
  float4 v = *(const float4*)(src + i);
  bf16x4 o; o[0]=to_b(v.x); o[1]=to_b(v.y); o[2]=to_b(v.z); o[3]=to_b(v.w);
  *(bf16x4*)(dst + i) = o;
}

__global__ __launch_bounds__(256) void k_init_h0(const float* __restrict__ hi_w, const float* __restrict__ hi_b,
                                                 bf16_t* __restrict__ h0b){
  int i = blockIdx.x*256 + threadIdx.x;           // [0, H)
  bf16_t vb = to_b(hi_w[i] + hi_b[i]);
  for (int b=0;b<Bb;++b) h0b[(size_t)b*Hh + i] = vb;
}

__global__ __launch_bounds__(256) void k_convert_x(const float* __restrict__ x, bf16_t* __restrict__ x_tm){
  size_t idx = ((size_t)blockIdx.x*256 + threadIdx.x)*8;
  int    i0  = (int)(idx % Ii);
  size_t m   = idx / Ii;                          // m = t*B + b
  int    t   = (int)(m / Bb), b = (int)(m % Bb);
  const float* s = x + ((size_t)b*Tt + t)*Ii + i0;
  float4 v0 = *(const float4*)s, v1 = *(const float4*)(s+4);
  bf16x8 o;
  o[0]=to_b(v0.x); o[1]=to_b(v0.y); o[2]=to_b(v0.z); o[3]=to_b(v0.w);
  o[4]=to_b(v1.x); o[5]=to_b(v1.y); o[6]=to_b(v1.z); o[7]=to_b(v1.w);
  *(bf16x8*)(x_tm + idx) = o;
}

// ---------- GEMM building blocks (encoder / decoder) ----------
template<int ROWS, int KB>
static __device__ __forceinline__ void stage(const bf16_t* __restrict__ g, long ld, long row0, int k0,
                                             char* __restrict__ ldsT){
  constexpr int SLOTS = KB/8;
  constexpr int PT    = ROWS*SLOTS/256;
  #pragma unroll
  for (int j=0;j<PT;++j){
    int c    = threadIdx.x + 256*j;
    int row  = c / SLOTS, slot = c % SLOTS;
    uint4 v  = *(const uint4*)(g + (row0+row)*ld + k0 + slot*8);
    *(uint4*)(ldsT + row*(KB*2) + ((slot*16) ^ ((row&7)<<4))) = v;
  }
}

template<int KB>
static __device__ __forceinline__ bf16x8 frag(const char* __restrict__ ldsT, int row, int kk, int lane){
  int kbyte = kk*64 + ((lane>>4)<<4);
  return *(const bf16x8*)(ldsT + row*(KB*2) + (kbyte ^ ((row&7)<<4)));
}

template<int EPI>
__global__ __launch_bounds__(256) void gemm128(const bf16_t* __restrict__ A, long lda,
                                               const bf16_t* __restrict__ Bw, long ldb,
                                               const float* __restrict__ bias,
                                               void* __restrict__ Cout, long ldc, int K){
  constexpr int TM=128, TN=128, KB=64;
  __shared__ char lds[(TM+TN)*KB*2];
  char* ldsA = lds;
  char* ldsB = lds + TM*KB*2;
  long m0 = (long)blockIdx.x * TM;
  long n0 = (long)blockIdx.y * TN;
  int w = threadIdx.x >> 6, lane = threadIdx.x & 63;
  int wm = w >> 1, wn = w & 1;
  f32x4_t acc[4][4] = {};
  for (int k0=0;k0<K;k0+=KB){
    __syncthreads();
    stage<TM,KB>(A,  lda, m0, k0, ldsA);
    stage<TN,KB>(Bw, ldb, n0, k0, ldsB);
    __syncthreads();
    #pragma unroll
    for (int kk=0;kk<KB/32;++kk){
      bf16x8 af[4], bfv[4];
      #pragma unroll
      for (int f=0;f<4;++f){ int r = wm*64 + f*16 + (lane&15); af[f]  = frag<KB>(ldsA, r, kk, lane); }
      #pragma unroll
      for (int f=0;f<4;++f){ int r = wn*64 + f*16 + (lane&15); bfv[f] = frag<KB>(ldsB, r, kk, lane); }
      #pragma unroll
      for (int i=0;i<4;++i)
        #pragma unroll
        for (int j=0;j<4;++j)
          acc[i][j] = __builtin_amdgcn_mfma_f32_16x16x32_bf16(af[i], bfv[j], acc[i][j], 0,0,0);
    }
  }
  #pragma unroll
  for (int i=0;i<4;++i)
    #pragma unroll
    for (int j=0;j<4;++j)
      #pragma unroll
      for (int e=0;e<4;++e){
        long row = m0 + wm*64 + i*16 + ((lane>>4)<<2) + e;
        long col = n0 + wn*64 + j*16 + (lane&15);
        float v = acc[i][j][e] + bias[col];
        if (EPI==0) ((bf16_t*)Cout)[row*ldc + col] = to_b(v);
        else        ((float*) Cout)[row*ldc + col] = v;
      }
}

// ---------- persistent recurrence kernel ----------
// 4 groups of 64 blocks (g = bid&3 -> a group's blocks cluster on 2 XCDs if
// XCD = bid%8, giving each XCD one group's A-slice in its L2).
// Block (g,n) owns batches 32g..+31, H-cols 32n..+31. W slice (128 KB) in LDS
// for the whole kernel. Per step: A (h_prev rows) staged via global_load_lds
// into double-buffered 16 KB LDS chunks with pre-swizzled global source;
// enc-read/h-write are cooperative coalesced u64 agent atomics exchanged
// through LDS; group barrier = per-step agent atomicAdd counter + tid0 poll.
__global__ __launch_bounds__(256, 1) void rec_persist(
    const bf16_t* __restrict__ h0b, const bf16_t* __restrict__ W,
    bf16_t* __restrict__ EH, float* __restrict__ hfinal,
    const float* __restrict__ rec_b, const float* __restrict__ hi_w, const float* __restrict__ hi_b,
    const float* __restrict__ dtp, const float* __restrict__ ap,
    unsigned* __restrict__ cnt)
{
  __shared__ uint4 lds4[163840/16];      // 160 KB: W (128K) + 2x16K A chunks
  char* lds = (char*)lds4;
  char* Wb  = lds;
  char* Ab0 = lds + 131072;
  char* Ab1 = lds + 147456;
  u64*  xbuf = (u64*)Ab0;                // epilogue exchange buffer (reuses Ab0)

  const int bid = blockIdx.x;
  const int g   = bid & 3;               // batch group
  const int n   = bid >> 2;              // H tile 0..63
  const int m0  = g * 32;
  const int n0  = n * 32;
  unsigned* gcnt = cnt + g*512;
  const int tid = threadIdx.x, w = tid >> 6, lane = tid & 63;
  const int boff = (w & 1) * 16, hoff = (w >> 1) * 16;

  // stage W rows n0..n0+31 (once)
  for (int r = 0; r < 32; ++r){
    uint4 v = *(const uint4*)(W + (size_t)(n0 + r)*Hh + tid*8);
    *(uint4*)(Wb + r*4096 + ((tid*16) ^ ((r&7)<<4))) = v;
  }
  __syncthreads();

  const float s  = 1.f/(1.f + __expf(-dtp[0]));
  const float av = ap[0];
  const int   batch_l = boff + (lane & 15);             // local batch 0..31
  const int   batch   = m0 + batch_l;
  const int   hcol0   = n0 + hoff + ((lane >> 4) << 2); // this lane's 4 H cols
  const int   lslot   = batch_l*8 + ((w>>1)*4 + (lane>>4));
  float rb[4], hm[4];
  #pragma unroll
  for (int e=0;e<4;++e){ rb[e] = rec_b[hcol0+e]; hm[e] = hi_w[hcol0+e] + hi_b[hcol0+e]; }

  // W-fragment addressing
  const int   wrow  = hoff + (lane & 15);
  const char* wbase = Wb + wrow*4096;
  const int   wxor  = (wrow & 7) << 4;
  const int   ksub  = (lane >> 4) * 16;
  // A-fragment addressing (within chunk buffer)
  const int   aoff  = batch_l * CHB;
  const int   axor  = (batch_l & 7) << 4;
  // staging: wave w covers rows w*8..w*8+8; issue i covers 2 rows
  const int   st_r  = (w << 3) + (lane >> 5);           // + 2*i
  const int   st_sb = (lane & 31) << 4;
  // cooperative enc/h addressing (thread tid -> batch tid>>3, colblock tid&7)
  const int   co_b  = m0 + (tid >> 3);
  const int   co_c  = n0 + (tid & 7)*4;

  for (int t = 0; t < Tt; ++t){
    const bf16_t* Asrc = (t==0) ? h0b : (EH + (size_t)(t-1)*(Bb*Hh));
    bf16_t* EHt = EH + (size_t)t*(Bb*Hh);

    // issue chunk 0 staging (oldest ops), then cooperative enc load into reg
    #pragma unroll
    for (int i=0;i<4;++i){
      int row = st_r + 2*i;
      int cb  = st_sb ^ ((row & 7) << 4);
      gl_lds16(Asrc + (size_t)(m0+row)*Hh + (cb>>1), Ab0 + (w<<12) + (i<<10));
    }
    u64 ecv = __hip_atomic_load((const u64*)(EHt + (size_t)co_b*Hh + co_c),
                                __ATOMIC_RELAXED, __HIP_MEMORY_SCOPE_AGENT);

    f32x4_t acc0 = {0.f,0.f,0.f,0.f}, acc1 = {0.f,0.f,0.f,0.f};
    #pragma unroll
    for (int c=0;c<NCH;++c){
      __syncthreads();   // full drain: chunk c staging (and step-start loads) complete
      if (c+1 < NCH){
        char* dst = ((c+1)&1) ? Ab1 : Ab0;
        #pragma unroll
        for (int i=0;i<4;++i){
          int row = st_r + 2*i;
          int cb  = st_sb ^ ((row & 7) << 4);
          gl_lds16(Asrc + (size_t)(m0+row)*Hh + (c+1)*CHC + (cb>>1), dst + (w<<12) + (i<<10));
        }
      }
      const char* ab = ((c&1) ? Ab1 : Ab0) + aoff;
      #pragma unroll
      for (int kk=0;kk<8;kk+=2){
        bf16x8 wa0 = *(const bf16x8*)(wbase + ((c*512 + kk*64     + ksub) ^ wxor));
        bf16x8 ha0 = *(const bf16x8*)(ab    + ((        kk*64     + ksub) ^ axor));
        acc0 = __builtin_amdgcn_mfma_f32_16x16x32_bf16(wa0, ha0, acc0, 0,0,0);
        bf16x8 wa1 = *(const bf16x8*)(wbase + ((c*512 + (kk+1)*64 + ksub) ^ wxor));
        bf16x8 ha1 = *(const bf16x8*)(ab    + ((        (kk+1)*64 + ksub) ^ axor));
        acc1 = __builtin_amdgcn_mfma_f32_16x16x32_bf16(wa1, ha1, acc1, 0,0,0);
      }
    }

    // epilogue: distribute enc via LDS, compute, pack h, cooperative store
    xbuf[tid] = ecv;
    __syncthreads();
    u64 ev = xbuf[lslot];
    u64 ov = 0;
    #pragma unroll
    for (int e=0;e<4;++e){
      float enc = b2f((unsigned short)(ev >> (16*e)));
      float pre = enc + av*(acc0[e] + acc1[e] + rb[e]);
      float th  = 1.f - 2.f/(__expf(2.f*pre) + 1.f);   // tanh
      hm[e] = (1.f - s)*hm[e] + s*th;
      ov |= ((u64)f2bbits(hm[e])) << (16*e);
    }
    xbuf[lslot] = ov;                    // same lane reads then writes its own slot
    __syncthreads();
    u64 hv = xbuf[tid];
    __hip_atomic_store((u64*)(EHt + (size_t)co_b*Hh + co_c), hv,
                       __ATOMIC_RELAXED, __HIP_MEMORY_SCOPE_AGENT);
    __syncthreads();                     // drains store acks (vmcnt0 before s_barrier)

    // group barrier: one counter per (group, step)
    if (tid == 0){
      __hip_atomic_fetch_add(gcnt + t, 1u, __ATOMIC_RELAXED, __HIP_MEMORY_SCOPE_AGENT);
      while (__hip_atomic_load(gcnt + t, __ATOMIC_RELAXED, __HIP_MEMORY_SCOPE_AGENT) < 64u) {}
    }
    __syncthreads();
  }

  // final hidden (f32) -> out tail
  #pragma unroll
  for (int e=0;e<4;++e) hfinal[(size_t)batch*Hh + hcol0 + e] = hm[e];
}

// ---------- launch ----------
extern "C" void kernel_launch(void* const* d_in, const int* in_sizes, int n_in,
                              void* d_out, int out_size, void* d_ws, size_t ws_size,
                              hipStream_t stream){
  const float* x     = (const float*)d_in[0];
  const float* dt    = (const float*)d_in[1];
  const float* a     = (const float*)d_in[2];
  const float* enc_w = (const float*)d_in[3];
  const float* enc_b = (const float*)d_in[4];
  const float* rec_w = (const float*)d_in[5];
  const float* rec_b = (const float*)d_in[6];
  const float* dec_w = (const float*)d_in[7];
  const float* dec_b = (const float*)d_in[8];
  const float* hi_w  = (const float*)d_in[9];
  const float* hi_b  = (const float*)d_in[10];
  float* out = (float*)d_out;

  // workspace carve-out (~333 MB)
  char* ws = (char*)d_ws;
  size_t off = 0;
  auto carve = [&](size_t bytes)->char*{ char* p = ws + off; off += (bytes + 255) & ~(size_t)255; return p; };
  bf16_t* x_tm   = (bf16_t*)carve((size_t)Tt*Bb*Ii*2);   // 64 MB
  bf16_t* EH     = (bf16_t*)carve((size_t)Tt*Bb*Hh*2);   // 256 MB  enc -> h history
  bf16_t* h0b    = (bf16_t*)carve((size_t)Bb*Hh*2);
  bf16_t* enc_wb = (bf16_t*)carve((size_t)Hh*Ii*2);
  bf16_t* rec_wb = (bf16_t*)carve((size_t)Hh*Hh*2);
  bf16_t* dec_wb = (bf16_t*)carve((size_t)Oo*Hh*2);
  unsigned* cnt  = (unsigned*)carve(4*512*4);             // per-(group,step) counters
  if (off > ws_size) return;  // diagnostic: leaves output zeroed

  // reset barrier counters every call (ws is not re-poisoned between replays)
  hipMemsetAsync(cnt, 0, 4*512*4, stream);

  // weights -> bf16
  k_f2b<<<(Hh*Ii)/1024, 256, 0, stream>>>(enc_wb, enc_w);
  k_f2b<<<(Hh*Hh)/1024, 256, 0, stream>>>(rec_wb, rec_w);
  k_f2b<<<(Oo*Hh)/1024, 256, 0, stream>>>(dec_wb, dec_w);
  k_init_h0<<<Hh/256, 256, 0, stream>>>(hi_w, hi_b, h0b);
  k_convert_x<<<((size_t)Tt*Bb*Ii/8)/256, 256, 0, stream>>>(x, x_tm);

  // encoder: EH[t*B+b, h] = x_tm @ enc_w^T + enc_b   (M=65536, K=512, N=2048)
  gemm128<0><<<dim3((Tt*Bb)/128, Hh/128), 256, 0, stream>>>(x_tm, Ii, enc_wb, Ii, enc_b, EH, Hh, Ii);

  // recurrence: one persistent cooperative kernel, 512 steps, per-group counters
  {
    float* hfinal = out + (size_t)Tt*Bb*Oo;
    void* args[] = { (void*)&h0b, (void*)&rec_wb, (void*)&EH, (void*)&hfinal,
                     (void*)&rec_b, (void*)&hi_w, (void*)&hi_b, (void*)&dt, (void*)&a,
                     (void*)&cnt };
    hipLaunchCooperativeKernel((const void*)rec_persist, dim3(REC_GRID), dim3(256), args, 0, stream);
  }

  // decoder: out[t*B+b, o] = EH @ dec_w^T + dec_b   (M=65536, K=2048, N=512)
  gemm128<1><<<dim3((Tt*Bb)/128, Oo/128), 256, 0, stream>>>(EH, Hh, dec_wb, Hh, dec_b, out, Oo, Hh);
}